// Round 1
// 151.169 us; speedup vs baseline: 1.0049x; 1.0049x over previous
//
#include <hip/hip_runtime.h>
#include <math.h>

#pragma clang fp contract(off)

// Problem constants
#define B_   128
#define CI_  16
#define CO_  32
#define H_   32
#define W_   32
#define HO_  30
#define WO_  30
#define P_   900                 // HO*WO
#define CP_  (CO_*P_)            // 28800
#define N_   ((size_t)B_*CP_)    // 3686400 elements per tensor
#define NBLK_CONV (4*30*8)       // conv grid blocks = 960 (UNCHANGED -> BN stats bitwise identical)

#define WSTRIDE_O 129600         // CI_*P_*9
#define WSTRIDE_C 8100           // P_*9

// d_out layout (4*N_ floats): [0,N)=soma, [N,2N)=spike, [2N,3N)=a_new, [3N,4N)=b_new.
// Slot [3N,4N) temporarily holds the f32 conv value; LIF reads it before
// overwriting with b_new.

// async global->LDS, 4B per lane. LDS dest is wave-uniform base + lane*4.
typedef __attribute__((address_space(1))) const unsigned int gas_uint;
typedef __attribute__((address_space(3))) unsigned int las_uint;
__device__ __forceinline__ void gload_lds4(const float* g, float* l) {
    __builtin_amdgcn_global_load_lds((gas_uint*)g, (las_uint*)l, 4, 0, 0);
}

// ---------------------------------------------------------------------------
// Kernel 1: locally-connected conv, async-staged + double-buffered.
// Same math as before: f32 sequential accumulation in (c,kh,kw) order, NO FMA.
// Block: 256 thr = 32 o x 8 w. Grid: (wtile=4, h=30, btile=8), 16 b per block.
// Weights for the whole block (32o x 8w x 9k = 2304 f32) staged per c into
// LDS via global_load_lds (dense global reads), ff tile (16b x 3r x 10c = 480)
// likewise. One barrier per c; prefetch of c+1 overlaps compute of c.
// Buffer indices are compile-time constants (loop stepped by 2) so the
// compiler can keep the prefetch async past the other buffer's ds_reads.
// ---------------------------------------------------------------------------
__global__ __launch_bounds__(256) void conv_kernel(
    const float* __restrict__ ff, const float* __restrict__ weight,
    const float* __restrict__ conv_bias, float* __restrict__ outf,
    double* __restrict__ part_sum, double* __restrict__ part_sumsq)
{
#pragma clang fp contract(off)
    const int tid = threadIdx.x;
    const int o  = tid >> 3;
    const int wi = tid & 7;
    const int wt = blockIdx.x;          // 0..3  (w0 = wt*8)
    const int h  = blockIdx.y;          // 0..29
    const int b0 = blockIdx.z * 16;     // 16 batches per block
    const int w  = wt * 8 + wi;
    const bool wv = (w < WO_);
    const int wwave = tid & ~63;        // wave-uniform lane-0 tid

    __shared__ float wg[2][2304];       // [buf][(o*8+w)*9+k]
    __shared__ float ffs[2][480];       // [buf][bb*30 + r*10 + cc]

    // --- precompute per-thread global float-offsets for staged elements ---
    // weights: element e = tid + q*256 -> (o,w,k); clamp OOB w (garbage read
    // only by invalid lanes; clamped so address stays in-bounds & finite).
    int woff[9];
#pragma unroll
    for (int q = 0; q < 9; ++q) {
        int e  = tid + q * 256;         // 0..2303, exact
        int oo = e / 72;
        int rem = e - oo * 72;
        int ww = rem / 9;
        int kk = rem - ww * 9;
        int wcl = wt * 8 + ww; if (wcl > WO_ - 1) wcl = WO_ - 1;
        woff[q] = oo * WSTRIDE_O + (h * WO_ + wcl) * 9 + kk;
    }
    // ff: elements tid and tid+256 (second guarded, 480 total)
    int foff[2];
    const bool fon2 = (tid < 224);
    {
        int e = tid;
        int bb = e / 30, rc = e - bb * 30, r = rc / 10, cc = rc - r * 10;
        int col = wt * 8 + cc; if (col > W_ - 1) col = W_ - 1;
        foff[0] = ((b0 + bb) * CI_) * (H_ * W_) + (h + r) * W_ + col;
        e = tid + 256;
        bb = e / 30; rc = e - bb * 30; r = rc / 10; cc = rc - r * 10;
        col = wt * 8 + cc; if (col > W_ - 1) col = W_ - 1;
        foff[1] = ((b0 + bb) * CI_) * (H_ * W_) + (h + r) * W_ + col;
    }

    float acc[16];
#pragma unroll
    for (int i = 0; i < 16; ++i) acc[i] = 0.f;

    // issue all async stage loads for channel c into buffer buf
    auto stage = [&](int c, int buf) {
        const float* wsrc = weight + c * WSTRIDE_C;
#pragma unroll
        for (int q = 0; q < 9; ++q)
            gload_lds4(wsrc + woff[q], &wg[buf][q * 256 + wwave]);
        const float* fsrc = ff + c * (H_ * W_);
        gload_lds4(fsrc + foff[0], &ffs[buf][wwave]);
        if (fon2) gload_lds4(fsrc + foff[1], &ffs[buf][256 + wwave]);
    };

    // accumulate one channel from buffer buf (buf is a literal at call sites)
    auto compute_c = [&](int buf) {
        float wk[9];
        const float* wl = &wg[buf][(o * 8 + wi) * 9];
#pragma unroll
        for (int k = 0; k < 9; ++k) wk[k] = wl[k];
        const float* fl = &ffs[buf][wi];
#pragma unroll
        for (int kh = 0; kh < 3; ++kh) {
#pragma unroll
            for (int kw = 0; kw < 3; ++kw) {
                const float wv_ = wk[kh * 3 + kw];
#pragma unroll
                for (int bb = 0; bb < 16; ++bb) {
                    float prod = wv_ * fl[bb * 30 + kh * 10 + kw];
                    acc[bb] = acc[bb] + prod;   // no FMA, (c,kh,kw) order
                }
            }
        }
    };

    stage(0, 0);
    __syncthreads();
    for (int cs = 0; cs < CI_; cs += 2) {
        if (cs + 1 < CI_) stage(cs + 1, 1);   // prefetch, overlaps compute
        compute_c(0);
        __syncthreads();                      // drains prefetch; protects buf0
        if (cs + 2 < CI_) stage(cs + 2, 0);
        compute_c(1);
        __syncthreads();
    }

    // epilogue: bias, park conv value, exact f64 per-block per-channel stats
    double s1 = 0.0, s2 = 0.0;
    if (wv) {
        const int pidx = o * P_ + h * WO_ + w;
        const float bias = conv_bias[pidx];
#pragma unroll
        for (int bb = 0; bb < 16; ++bb) {
            float v = acc[bb] + bias;                    // f32, same as ref
            size_t n = (size_t)(b0 + bb) * CP_ + (size_t)pidx;
            outf[3 * N_ + n] = v;                        // park conv in b_new slot
            double vd = (double)v;
            s1 += vd; s2 += vd * vd;
        }
    }
#pragma unroll
    for (int d = 1; d < 8; d <<= 1) { s1 += __shfl_xor(s1, d); s2 += __shfl_xor(s2, d); }
    if (wi == 0) {
        int blk = (blockIdx.z * 30 + blockIdx.y) * 4 + blockIdx.x;   // 0..959
        part_sum  [blk * CO_ + o] = s1;
        part_sumsq[blk * CO_ + o] = s2;
    }
}

// ---------------------------------------------------------------------------
// Kernel 2: BN finalize — deterministic f64 reduction of partials, then
// f32 mean / inv_std per channel. UNCHANGED (bitwise-identical Mb).
// ---------------------------------------------------------------------------
__global__ __launch_bounds__(256) void bn_finalize(
    const double* __restrict__ part_sum, const double* __restrict__ part_sumsq,
    float* __restrict__ Mb)
{
#pragma clang fp contract(off)
    const int o = blockIdx.x;
    const int tid = threadIdx.x;
    double s1 = 0.0, s2 = 0.0;
    for (int i = tid; i < NBLK_CONV; i += 256) {
        s1 += part_sum[i * CO_ + o];
        s2 += part_sumsq[i * CO_ + o];
    }
    __shared__ double r1[256], r2[256];
    r1[tid] = s1; r2[tid] = s2;
    __syncthreads();
    for (int s = 128; s > 0; s >>= 1) {
        if (tid < s) { r1[tid] += r1[tid + s]; r2[tid] += r2[tid + s]; }
        __syncthreads();
    }
    if (tid == 0) {
        const double cnt = (double)(B_ * (size_t)P_);
        double mean = r1[0] / cnt;
        float meanf = (float)mean;
        double md = (double)meanf;
        double var = r2[0] / cnt - 2.0 * md * (r1[0] / cnt) + md * md;
        float varf = (float)var;
        float invf = 1.0f / sqrtf(varf + 1e-5f);
        Mb[o]       = meanf;
        Mb[CO_ + o] = invf;
    }
}

// ---------------------------------------------------------------------------
// Kernel 3: fused recurrent-bmm + LIF, all f32, np op order, no FMA.
// tau_kernel folded in (identical f32 expressions: expf(-0.5f/tau)).
// Double-buffered spike tile -> one barrier per batch instead of two.
// Block: 512 thr = 32 ch (i) x 16 p; grid (57 ptiles, 16 bgroups of 8).
// ---------------------------------------------------------------------------
__global__ __launch_bounds__(512) void lif_rec_kernel(
    float* __restrict__ outf, const float* __restrict__ local_rec,
    const float* __restrict__ tau_m, const float* __restrict__ tau_adp,
    const float* __restrict__ tau_a, const float* __restrict__ Mb,
    const float* __restrict__ gamma, const float* __restrict__ beta,
    const float* __restrict__ fb, const float* __restrict__ soma_t,
    const float* __restrict__ spk_t, const float* __restrict__ a_curr,
    const float* __restrict__ b_t)
{
#pragma clang fp contract(off)
    const int tid = threadIdx.x;
    const int pp  = tid & 15;
    const int i   = tid >> 4;            // channel 0..31
    const int p   = blockIdx.x * 16 + pp;
    const bool pv = (p < P_);
    const int b0  = blockIdx.y * 8;

    float L[32];
    float meanf = 0.f, invf = 0.f, gm = 0.f, be = 0.f;
    float al = 0.f, rh = 0.f, et = 0.f;
    int rem = 0;
    if (pv) {
        const float4* lp = reinterpret_cast<const float4*>(local_rec + (size_t)p * (CO_ * CO_) + i * CO_);
#pragma unroll
        for (int q = 0; q < 8; ++q) {
            float4 v = lp[q];
            L[4 * q] = v.x; L[4 * q + 1] = v.y; L[4 * q + 2] = v.z; L[4 * q + 3] = v.w;
        }
        rem = i * P_ + p;
        meanf = Mb[i]; invf = Mb[CO_ + i];
        gm = gamma[i]; be = beta[i];
        // identical ops to the old tau_kernel: f32 divide then f32 exp
        al = expf(-0.5f / tau_m[rem]);
        rh = expf(-0.5f / tau_adp[rem]);
        et = expf(-0.5f / tau_a[rem]);
    }

    __shared__ float sp[2][CO_][16];
    for (int bb = 0; bb < 8; ++bb) {
        const int b = b0 + bb;
        const size_t n = (size_t)b * CP_ + (size_t)rem;
        const int cb = bb & 1;
        if (pv) sp[cb][i][pp] = spk_t[n];
        __syncthreads();                 // writes visible; prev parity buffer free
        if (pv) {
            // rec: sequential f32 dot over j, no FMA (np einsum order)
            float rec = 0.f;
#pragma unroll
            for (int j = 0; j < CO_; ++j) {
                float prod = L[j] * sp[cb][j][pp];
                rec = rec + prod;
            }

            float cv = outf[3 * N_ + n];         // parked conv value (read first!)
            float sk = sp[cb][i][pp];

            // BN exactly as reference
            float t  = cv - meanf;
            float x  = t * invf;
            float xg = x * gm;
            float cx = xg + be;
            cx = cx + rec;

            // b_new = rho*b_t + (1-rho)*spk
            float rb  = rh * b_t[n];
            float omr = 1.0f - rh;
            float os  = omr * sk;
            float bn  = rb + os;
            // new_thre = 0.1 + 1.8*b_new
            float tb = 1.8f * bn;
            float th = 0.1f + tb;
            // a_new = eta*a_curr + fb
            float ea = et * a_curr[n];
            float an = ea + fb[n];
            // sigmoid
            float sg = 1.0f / (1.0f + expf(-an));
            // soma_new = alpha*soma + (sig-0.5) + cx - thre*spk  (left-to-right)
            float as = al * soma_t[n];
            float s5 = sg - 0.5f;
            float u1 = as + s5;
            float u2 = u1 + cx;
            float ts = th * sk;
            float sn = u2 - ts;

            outf[n]          = sn;
            outf[N_ + n]     = ((sn - th) > 0.0f) ? 1.f : 0.f;
            outf[2 * N_ + n] = an;
            outf[3 * N_ + n] = bn;                                // overwrites conv
        }
    }
}

extern "C" void kernel_launch(void* const* d_in, const int* in_sizes, int n_in,
                              void* d_out, int out_size, void* d_ws, size_t ws_size,
                              hipStream_t stream)
{
    const float* ff        = (const float*)d_in[0];
    const float* fb        = (const float*)d_in[1];
    const float* soma_t    = (const float*)d_in[2];
    const float* spk_t     = (const float*)d_in[3];
    const float* a_curr    = (const float*)d_in[4];
    const float* b_t       = (const float*)d_in[5];
    const float* weight    = (const float*)d_in[6];
    const float* conv_bias = (const float*)d_in[7];
    const float* local_rec = (const float*)d_in[8];
    const float* gamma     = (const float*)d_in[9];
    const float* beta      = (const float*)d_in[10];
    const float* tau_m     = (const float*)d_in[11];
    const float* tau_adp   = (const float*)d_in[12];
    const float* tau_a     = (const float*)d_in[13];

    // ws: f64 partials then Mb (~0.5 MB total)
    double* part_sum = (double*)d_ws;                       // NBLK_CONV*CO_
    double* part_sq  = part_sum + (size_t)NBLK_CONV * CO_;  // NBLK_CONV*CO_
    float*  Mb       = (float*)(part_sq + (size_t)NBLK_CONV * CO_);  // 64

    float* outf = (float*)d_out;

    conv_kernel<<<dim3(4, 30, 8), 256, 0, stream>>>(
        ff, weight, conv_bias, outf, part_sum, part_sq);
    bn_finalize<<<dim3(CO_), 256, 0, stream>>>(part_sum, part_sq, Mb);
    lif_rec_kernel<<<dim3(57, 16), 512, 0, stream>>>(
        outf, local_rec, tau_m, tau_adp, tau_a, Mb, gamma, beta,
        fb, soma_t, spk_t, a_curr, b_t);
}